// Round 4
// baseline (1622.604 us; speedup 1.0000x reference)
//
#include <hip/hip_runtime.h>
#include <cstdint>
#include <cstddef>

// Problem constants (match the JAX reference)
#define MM 2
#define DD 128
#define RR 8
#define NN0 8192
#define LLV 32
#define KK 4096
#define NTHAX 1000
#define NTOT (NN0 + LLV*KK)     // 139264
#define NB 16                   // nodes per chunk
#define CHN 264                 // max chunks per level: ceil((4096 + 8*15)/16) = 264

// ---------------------------------------------------------------------------
// Preprocess: per level, counting-sort node indices by rule into NB-padded
// chunks so each level-kernel block handles exactly one rule.
// ---------------------------------------------------------------------------
__global__ void prep_kernel(const int* __restrict__ rule_ids,
                            int* __restrict__ chunk_nodes,   // [LLV][CHN][NB]
                            int* __restrict__ chunk_rule,    // [LLV][CHN]
                            int* __restrict__ nchunks)       // [LLV]
{
  const int l = blockIdx.x, t = threadIdx.x;
  __shared__ int cnt[RR], start[RR], fill[RR];
  if (t < RR){ cnt[t] = 0; fill[t] = 0; }
  __syncthreads();
  for (int k = t; k < KK; k += blockDim.x) atomicAdd(&cnt[rule_ids[l*KK + k]], 1);
  __syncthreads();
  if (t == 0){
    int s = 0;
    for (int r = 0; r < RR; ++r){
      start[r] = s;
      int pad = (cnt[r] + NB - 1)/NB*NB;
      for (int c = s/NB; c < (s+pad)/NB; ++c) chunk_rule[l*CHN + c] = r;
      s += pad;
    }
    nchunks[l] = s/NB;
  }
  __syncthreads();
  for (int i = t; i < CHN*NB; i += blockDim.x) chunk_nodes[l*CHN*NB + i] = -1;
  __syncthreads();
  for (int k = t; k < KK; k += blockDim.x){
    int r = rule_ids[l*KK + k];
    int p = start[r] + atomicAdd(&fill[r], 1);
    chunk_nodes[l*CHN*NB + p] = k;
  }
}

// ---------------------------------------------------------------------------
// Init nodes: store[i][m][d] = thax_table[m][thax[i]][d] * sigmoid(s*w + b)
// ---------------------------------------------------------------------------
__global__ void init_kernel(const int* __restrict__ thax_ids, const int* __restrict__ sine_ids,
                            const float* __restrict__ thax_table,
                            const float* __restrict__ sine_w, const float* __restrict__ sine_b,
                            float* __restrict__ store)
{
  int idx = blockIdx.x*blockDim.x + threadIdx.x;    // over NN0*MM*DD
  if (idx >= NN0*MM*DD) return;
  int i = idx >> 8;            // node
  int md = idx & 255;
  int m = md >> 7, d = md & 127;
  float emb = thax_table[((size_t)m*NTHAX + thax_ids[i])*DD + d];
  float s = (float)sine_ids[i];
  float z = s*sine_w[m*DD + d] + sine_b[m*DD + d];
  float sig = 1.f/(1.f + expf(-z));
  store[idx] = emb*sig;
}

// ---------------------------------------------------------------------------
// Totals: tot_pos / tot_neg for the pos_weight factor
// ---------------------------------------------------------------------------
__global__ void totals_kernel(const float* __restrict__ pos, const float* __restrict__ neg,
                              float* __restrict__ totals)
{
  float sp = 0.f, sn = 0.f;
  for (int n = blockIdx.x*blockDim.x + threadIdx.x; n < NTOT; n += gridDim.x*blockDim.x){
    sp += pos[n]; sn += neg[n];
  }
  #pragma unroll
  for (int s = 1; s < 64; s <<= 1){ sp += __shfl_xor(sp, s, 64); sn += __shfl_xor(sn, s, 64); }
  if ((threadIdx.x & 63) == 0){ atomicAdd(&totals[0], sp); atomicAdd(&totals[1], sn); }
}

// ---------------------------------------------------------------------------
// One level: per block = one (chunk of 16 same-rule nodes, ensemble member m).
// X staged in LDS; 2-layer MLP with 2-node x 4-e register tiles, float4 loads.
// Weights (one (m,r): 192KB fp32) stream from L1/L2, reused across 16 nodes.
// 256 threads, ~24KB LDS -> 4 blocks/CU; ~528 blocks/level for load balance.
// ---------------------------------------------------------------------------
__global__ __launch_bounds__(256, 4) void level_kernel(
    float* __restrict__ store,
    const int* __restrict__ parents,      // [LLV][KK][2]
    const int* __restrict__ chunk_nodes,  // [LLV][CHN][NB]
    const int* __restrict__ chunk_rule,   // [LLV][CHN]
    const int* __restrict__ nchunks,      // [LLV]
    const float* __restrict__ W1, const float* __restrict__ b1,
    const float* __restrict__ W2, const float* __restrict__ b2,
    int level)
{
  const int c = blockIdx.x;
  if (c >= nchunks[level]) return;
  const int m = blockIdx.y;
  const int r = chunk_rule[level*CHN + c];
  __shared__ float X[NB][2*DD];
  __shared__ float Hs[NB][DD];
  __shared__ int nd[NB];
  const int t = threadIdx.x;
  if (t < NB) nd[t] = chunk_nodes[(level*CHN + c)*NB + t];
  __syncthreads();

  // Stage concatenated parent vectors: X[n][0:128]=store[p0][m], X[n][128:256]=store[p1][m]
  const int* parL = parents + (size_t)level*KK*2;
  #pragma unroll
  for (int i = 0; i < 16; ++i){
    int idx = i*256 + t;                  // 0..4095
    int n = idx >> 8, d = idx & 255;
    int node = nd[n];
    float v = 0.f;
    if (node >= 0){
      int p = parL[node*2 + (d >> 7)];
      v = store[(size_t)p*(MM*DD) + m*DD + (d & 127)];
    }
    X[n][d] = v;
  }
  __syncthreads();

  const int ej = t & 31, ni = t >> 5;     // 32 e-groups x 8 node-groups
  const int e0 = ej*4, n0 = ni*2;

  // Layer 1: h = relu(x @ W1 + b1)
  const float* W1p = W1 + (size_t)(m*RR + r)*(2*DD)*DD;
  float acc0[4] = {0,0,0,0}, acc1[4] = {0,0,0,0};
  for (int d4 = 0; d4 < 2*DD; d4 += 4){
    float4 xa4 = *(const float4*)&X[n0][d4];
    float4 xb4 = *(const float4*)&X[n0+1][d4];
    float xa[4] = {xa4.x, xa4.y, xa4.z, xa4.w};
    float xb[4] = {xb4.x, xb4.y, xb4.z, xb4.w};
    #pragma unroll
    for (int i = 0; i < 4; ++i){
      float4 w4 = *(const float4*)&W1p[(size_t)(d4+i)*DD + e0];
      float w[4] = {w4.x, w4.y, w4.z, w4.w};
      #pragma unroll
      for (int j = 0; j < 4; ++j){
        acc0[j] = fmaf(xa[i], w[j], acc0[j]);
        acc1[j] = fmaf(xb[i], w[j], acc1[j]);
      }
    }
  }
  const float* b1p = b1 + (m*RR + r)*DD;
  #pragma unroll
  for (int j = 0; j < 4; ++j){
    Hs[n0][e0+j]   = fmaxf(acc0[j] + b1p[e0+j], 0.f);
    Hs[n0+1][e0+j] = fmaxf(acc1[j] + b1p[e0+j], 0.f);
  }
  __syncthreads();

  // Layer 2: out = h @ W2 + b2
  const float* W2p = W2 + (size_t)(m*RR + r)*DD*DD;
  float c0[4] = {0,0,0,0}, c1[4] = {0,0,0,0};
  for (int e4 = 0; e4 < DD; e4 += 4){
    float4 ha4 = *(const float4*)&Hs[n0][e4];
    float4 hb4 = *(const float4*)&Hs[n0+1][e4];
    float ha[4] = {ha4.x, ha4.y, ha4.z, ha4.w};
    float hb[4] = {hb4.x, hb4.y, hb4.z, hb4.w};
    #pragma unroll
    for (int i = 0; i < 4; ++i){
      float4 w4 = *(const float4*)&W2p[(size_t)(e4+i)*DD + e0];
      float w[4] = {w4.x, w4.y, w4.z, w4.w};
      #pragma unroll
      for (int j = 0; j < 4; ++j){
        c0[j] = fmaf(ha[i], w[j], c0[j]);
        c1[j] = fmaf(hb[i], w[j], c1[j]);
      }
    }
  }
  const float* b2p = b2 + (m*RR + r)*DD;
  const int nodeA = nd[n0], nodeB = nd[n0+1];
  const size_t obase = (size_t)(NN0 + level*KK);
  if (nodeA >= 0){
    float4 o = make_float4(c0[0]+b2p[e0], c0[1]+b2p[e0+1], c0[2]+b2p[e0+2], c0[3]+b2p[e0+3]);
    *(float4*)&store[(obase + nodeA)*(MM*DD) + m*DD + e0] = o;
  }
  if (nodeB >= 0){
    float4 o = make_float4(c1[0]+b2p[e0], c1[1]+b2p[e0+1], c1[2]+b2p[e0+2], c1[3]+b2p[e0+3]);
    *(float4*)&store[(obase + nodeB)*(MM*DD) + m*DD + e0] = o;
  }
}

// ---------------------------------------------------------------------------
// Eval: wave-per-node dot with w_eval (both m in one wave), stable BCE,
// float atomics into zeroed d_out = [loss(2), posOK(2), negOK(2)]
// ---------------------------------------------------------------------------
__global__ void eval_kernel(const float* __restrict__ store,
                            const float* __restrict__ pos_cnt, const float* __restrict__ neg_cnt,
                            const float* __restrict__ w_eval, const float* __restrict__ b_eval,
                            const float* __restrict__ totals, float* __restrict__ out)
{
  const int t = threadIdx.x, lane = t & 63;
  const int gw = blockIdx.x*(blockDim.x >> 6) + (t >> 6);
  const int nw = gridDim.x*(blockDim.x >> 6);
  float4 wv = *(const float4*)&w_eval[4*lane];          // lanes 0-31 -> m=0, 32-63 -> m=1
  const int m = (lane >= 32) ? 1 : 0;
  const float be = b_eval[m];
  const float tp = totals[0], tn = totals[1];
  const float pw = (tp > 0.f) ? (tn / fmaxf(tp, 1.f)) : 1.f;   // POS_WEIGHT_EXTRA = 1
  float loss = 0.f, pOK = 0.f, nOK = 0.f;
  for (int n = gw; n < NTOT; n += nw){
    float4 v = *(const float4*)&store[(size_t)n*(MM*DD) + 4*lane];
    float p = v.x*wv.x + v.y*wv.y + v.z*wv.z + v.w*wv.w;
    #pragma unroll
    for (int s = 1; s < 32; s <<= 1) p += __shfl_xor(p, s, 64);   // reduce within each m-half
    const float val = p + be;
    if ((lane & 31) == 0){
      const float pc = pos_cnt[n], nc = neg_cnt[n];
      const float cnt = pc + nc;
      if (cnt > 0.f){
        float gold = pc / fmaxf(cnt, 1.f);
        float e = log1pf(expf(-fabsf(val)));
        float sp_pos = e + fmaxf(val, 0.f);     // softplus(val)
        float sp_neg = e + fmaxf(-val, 0.f);    // softplus(-val)
        loss += cnt * (pw*gold*sp_neg + (1.f - gold)*sp_pos);
      }
      pOK += (val >= 0.f) ? pc : 0.f;
      nOK += (val <  0.f) ? nc : 0.f;
    }
  }
  if ((lane & 31) == 0){
    atomicAdd(&out[m],     loss);
    atomicAdd(&out[2 + m], pOK);
    atomicAdd(&out[4 + m], nOK);
  }
}

// ---------------------------------------------------------------------------
extern "C" void kernel_launch(void* const* d_in, const int* in_sizes, int n_in,
                              void* d_out, int out_size, void* d_ws, size_t ws_size,
                              hipStream_t stream)
{
  const int*   thax_ids   = (const int*)d_in[0];
  const int*   sine_ids   = (const int*)d_in[1];
  const int*   parents    = (const int*)d_in[2];
  const int*   rule_ids   = (const int*)d_in[3];
  const float* pos_cnt    = (const float*)d_in[4];
  const float* neg_cnt    = (const float*)d_in[5];
  const float* thax_table = (const float*)d_in[6];
  const float* sine_w     = (const float*)d_in[7];
  const float* sine_b     = (const float*)d_in[8];
  const float* W1         = (const float*)d_in[9];
  const float* b1         = (const float*)d_in[10];
  const float* W2         = (const float*)d_in[11];
  const float* b2         = (const float*)d_in[12];
  const float* w_eval     = (const float*)d_in[13];
  const float* b_eval     = (const float*)d_in[14];

  char* ws = (char*)d_ws;
  float* store = (float*)ws;
  size_t off = (size_t)NTOT*MM*DD*sizeof(float);            // 142.6 MB
  int* chunk_nodes = (int*)(ws + off); off += (size_t)LLV*CHN*NB*sizeof(int);
  int* chunk_rule  = (int*)(ws + off); off += (size_t)LLV*CHN*sizeof(int);
  int* nchunks     = (int*)(ws + off); off += (size_t)LLV*sizeof(int);
  float* totals    = (float*)(ws + off); off += 2*sizeof(float);

  hipMemsetAsync(d_out, 0, 6*sizeof(float), stream);
  hipMemsetAsync(totals, 0, 2*sizeof(float), stream);

  prep_kernel<<<LLV, 256, 0, stream>>>(rule_ids, chunk_nodes, chunk_rule, nchunks);
  init_kernel<<<(NN0*MM*DD + 255)/256, 256, 0, stream>>>(thax_ids, sine_ids, thax_table,
                                                         sine_w, sine_b, store);
  totals_kernel<<<64, 256, 0, stream>>>(pos_cnt, neg_cnt, totals);

  for (int l = 0; l < LLV; ++l)
    level_kernel<<<dim3(CHN, MM), 256, 0, stream>>>(store, parents, chunk_nodes, chunk_rule,
                                                    nchunks, W1, b1, W2, b2, l);

  eval_kernel<<<256, 256, 0, stream>>>(store, pos_cnt, neg_cnt, w_eval, b_eval, totals, (float*)d_out);
}

// Round 5
// 1347.163 us; speedup vs baseline: 1.2045x; 1.2045x over previous
//
#include <hip/hip_runtime.h>
#include <cstdint>
#include <cstddef>

// Problem constants (match the JAX reference)
#define MM 2
#define DD 128
#define RR 8
#define NN0 8192
#define LLV 32
#define KK 4096
#define NTHAX 1000
#define NTOT (NN0 + LLV*KK)     // 139264
#define NB 16                   // nodes per chunk
#define CHN 264                 // max chunks per level: ceil((4096 + 8*15)/16) = 264

// ---------------------------------------------------------------------------
// Preprocess: per level, counting-sort node indices by rule into NB-padded
// chunks so each level-kernel block handles exactly one rule.
// ---------------------------------------------------------------------------
__global__ void prep_kernel(const int* __restrict__ rule_ids,
                            int* __restrict__ chunk_nodes,   // [LLV][CHN][NB]
                            int* __restrict__ chunk_rule,    // [LLV][CHN]
                            int* __restrict__ nchunks)       // [LLV]
{
  const int l = blockIdx.x, t = threadIdx.x;
  __shared__ int cnt[RR], start[RR], fill[RR];
  if (t < RR){ cnt[t] = 0; fill[t] = 0; }
  __syncthreads();
  for (int k = t; k < KK; k += blockDim.x) atomicAdd(&cnt[rule_ids[l*KK + k]], 1);
  __syncthreads();
  if (t == 0){
    int s = 0;
    for (int r = 0; r < RR; ++r){
      start[r] = s;
      int pad = (cnt[r] + NB - 1)/NB*NB;
      for (int c = s/NB; c < (s+pad)/NB; ++c) chunk_rule[l*CHN + c] = r;
      s += pad;
    }
    nchunks[l] = s/NB;
  }
  __syncthreads();
  for (int i = t; i < CHN*NB; i += blockDim.x) chunk_nodes[l*CHN*NB + i] = -1;
  __syncthreads();
  for (int k = t; k < KK; k += blockDim.x){
    int r = rule_ids[l*KK + k];
    int p = start[r] + atomicAdd(&fill[r], 1);
    chunk_nodes[l*CHN*NB + p] = k;
  }
}

// ---------------------------------------------------------------------------
// Init nodes: store[i][m][d] = thax_table[m][thax[i]][d] * sigmoid(s*w + b)
// ---------------------------------------------------------------------------
__global__ void init_kernel(const int* __restrict__ thax_ids, const int* __restrict__ sine_ids,
                            const float* __restrict__ thax_table,
                            const float* __restrict__ sine_w, const float* __restrict__ sine_b,
                            float* __restrict__ store)
{
  int idx = blockIdx.x*blockDim.x + threadIdx.x;    // over NN0*MM*DD
  if (idx >= NN0*MM*DD) return;
  int i = idx >> 8;            // node
  int md = idx & 255;
  int m = md >> 7, d = md & 127;
  float emb = thax_table[((size_t)m*NTHAX + thax_ids[i])*DD + d];
  float s = (float)sine_ids[i];
  float z = s*sine_w[m*DD + d] + sine_b[m*DD + d];
  float sig = 1.f/(1.f + expf(-z));
  store[idx] = emb*sig;
}

// ---------------------------------------------------------------------------
// Totals: tot_pos / tot_neg for the pos_weight factor
// ---------------------------------------------------------------------------
__global__ void totals_kernel(const float* __restrict__ pos, const float* __restrict__ neg,
                              float* __restrict__ totals)
{
  float sp = 0.f, sn = 0.f;
  for (int n = blockIdx.x*blockDim.x + threadIdx.x; n < NTOT; n += gridDim.x*blockDim.x){
    sp += pos[n]; sn += neg[n];
  }
  #pragma unroll
  for (int s = 1; s < 64; s <<= 1){ sp += __shfl_xor(sp, s, 64); sn += __shfl_xor(sn, s, 64); }
  if ((threadIdx.x & 63) == 0){ atomicAdd(&totals[0], sp); atomicAdd(&totals[1], sn); }
}

// ---------------------------------------------------------------------------
// One level, structure C:
//   block = (chunk of 16 same-rule nodes, member m), 256 threads = 4 waves.
//   wave ks (0..3) owns a K-quarter; thread = (ej 0..31, ni 0..1) computes
//   8 nodes x 4 outputs (32 acc) for its K-quarter.  Weight traffic 0.5 B/FMA.
//   X is read directly from store via half-wave-uniform float4 broadcasts
//   (no LDS staging).  Per-layer LDS reduction sums the 4 K-quarters.
// ---------------------------------------------------------------------------
__global__ __launch_bounds__(256, 3) void level_kernel(
    float* __restrict__ store,
    const int* __restrict__ parents,      // [LLV][KK][2]
    const int* __restrict__ chunk_nodes,  // [LLV][CHN][NB]
    const int* __restrict__ chunk_rule,   // [LLV][CHN]
    const int* __restrict__ nchunks,      // [LLV]
    const float* __restrict__ W1, const float* __restrict__ b1,
    const float* __restrict__ W2, const float* __restrict__ b2,
    int level)
{
  const int c = blockIdx.x;
  if (c >= nchunks[level]) return;
  const int m = blockIdx.y;
  const int r = chunk_rule[level*CHN + c];

  __shared__ float RED[4][NB][32][4];   // 32 KB: [ks][node][ej][4e] partials
  __shared__ float Hlds[NB][DD];        // 8 KB : layer-1 activations
  __shared__ int nd[NB];
  __shared__ int par[NB][2];

  const int t  = threadIdx.x;
  const int ej = t & 31;
  const int ni = (t >> 5) & 1;
  const int ks = t >> 6;                // wave index = K-quarter
  const int e0 = ej * 4;

  if (t < NB){
    int node = chunk_nodes[(level*CHN + c)*NB + t];
    nd[t] = node;
    const int* parL = parents + (size_t)level*KK*2;
    int p0 = 0, p1 = 0;
    if (node >= 0){ p0 = parL[node*2]; p1 = parL[node*2 + 1]; }
    par[t][0] = p0; par[t][1] = p1;
  }
  __syncthreads();

  // ---------------- Layer 1: K rows [ks*64, ks*64+64) ----------------
  // x for those rows comes from parent (ks>>1), columns (ks&1)*64 + kl.
  const float* W1p = W1 + (size_t)(m*RR + r)*(2*DD)*DD + (size_t)(ks*64)*DD;
  const int psel = ks >> 1, koff = (ks & 1)*64;

  int xoff[8];
  #pragma unroll
  for (int j = 0; j < 8; ++j)
    xoff[j] = par[ni*8 + j][psel]*(MM*DD) + m*DD + koff;

  float acc[8][4];
  #pragma unroll
  for (int j = 0; j < 8; ++j){ acc[j][0]=0.f; acc[j][1]=0.f; acc[j][2]=0.f; acc[j][3]=0.f; }

  for (int kl = 0; kl < 64; kl += 4){
    float4 xq[8];
    #pragma unroll
    for (int j = 0; j < 8; ++j) xq[j] = *(const float4*)(store + xoff[j] + kl);
    #pragma unroll
    for (int i = 0; i < 4; ++i){
      float4 w4 = *(const float4*)&W1p[(size_t)(kl + i)*DD + e0];
      #pragma unroll
      for (int j = 0; j < 8; ++j){
        float xv = (i==0) ? xq[j].x : (i==1) ? xq[j].y : (i==2) ? xq[j].z : xq[j].w;
        acc[j][0] = fmaf(xv, w4.x, acc[j][0]);
        acc[j][1] = fmaf(xv, w4.y, acc[j][1]);
        acc[j][2] = fmaf(xv, w4.z, acc[j][2]);
        acc[j][3] = fmaf(xv, w4.w, acc[j][3]);
      }
    }
  }

  #pragma unroll
  for (int j = 0; j < 8; ++j)
    *(float4*)&RED[ks][ni*8 + j][ej][0] = make_float4(acc[j][0], acc[j][1], acc[j][2], acc[j][3]);
  __syncthreads();

  // reduce 4 K-quarters, add bias, relu, write Hlds.  512 sets, 2 per thread.
  {
    const float* b1p = b1 + (m*RR + r)*DD;
    #pragma unroll
    for (int s2 = 0; s2 < 2; ++s2){
      int s = t*2 + s2;                 // 0..511
      int n = s >> 5, e2 = s & 31;
      float4 a0 = *(const float4*)&RED[0][n][e2][0];
      float4 a1 = *(const float4*)&RED[1][n][e2][0];
      float4 a2 = *(const float4*)&RED[2][n][e2][0];
      float4 a3 = *(const float4*)&RED[3][n][e2][0];
      float4 bb = *(const float4*)&b1p[e2*4];
      float4 h;
      h.x = fmaxf(a0.x + a1.x + a2.x + a3.x + bb.x, 0.f);
      h.y = fmaxf(a0.y + a1.y + a2.y + a3.y + bb.y, 0.f);
      h.z = fmaxf(a0.z + a1.z + a2.z + a3.z + bb.z, 0.f);
      h.w = fmaxf(a0.w + a1.w + a2.w + a3.w + bb.w, 0.f);
      *(float4*)&Hlds[n][e2*4] = h;
    }
  }
  __syncthreads();

  // ---------------- Layer 2: K rows [ks*32, ks*32+32) ----------------
  const float* W2p = W2 + (size_t)(m*RR + r)*DD*DD + (size_t)(ks*32)*DD;

  #pragma unroll
  for (int j = 0; j < 8; ++j){ acc[j][0]=0.f; acc[j][1]=0.f; acc[j][2]=0.f; acc[j][3]=0.f; }

  for (int kl = 0; kl < 32; kl += 4){
    float4 xq[8];
    #pragma unroll
    for (int j = 0; j < 8; ++j) xq[j] = *(const float4*)&Hlds[ni*8 + j][ks*32 + kl];
    #pragma unroll
    for (int i = 0; i < 4; ++i){
      float4 w4 = *(const float4*)&W2p[(size_t)(kl + i)*DD + e0];
      #pragma unroll
      for (int j = 0; j < 8; ++j){
        float xv = (i==0) ? xq[j].x : (i==1) ? xq[j].y : (i==2) ? xq[j].z : xq[j].w;
        acc[j][0] = fmaf(xv, w4.x, acc[j][0]);
        acc[j][1] = fmaf(xv, w4.y, acc[j][1]);
        acc[j][2] = fmaf(xv, w4.z, acc[j][2]);
        acc[j][3] = fmaf(xv, w4.w, acc[j][3]);
      }
    }
  }

  #pragma unroll
  for (int j = 0; j < 8; ++j)
    *(float4*)&RED[ks][ni*8 + j][ej][0] = make_float4(acc[j][0], acc[j][1], acc[j][2], acc[j][3]);
  __syncthreads();

  // reduce, add b2, write result rows to store
  {
    const float* b2p = b2 + (m*RR + r)*DD;
    const size_t obase = (size_t)(NN0 + level*KK);
    #pragma unroll
    for (int s2 = 0; s2 < 2; ++s2){
      int s = t*2 + s2;
      int n = s >> 5, e2 = s & 31;
      int node = nd[n];
      if (node < 0) continue;
      float4 a0 = *(const float4*)&RED[0][n][e2][0];
      float4 a1 = *(const float4*)&RED[1][n][e2][0];
      float4 a2 = *(const float4*)&RED[2][n][e2][0];
      float4 a3 = *(const float4*)&RED[3][n][e2][0];
      float4 bb = *(const float4*)&b2p[e2*4];
      float4 o;
      o.x = a0.x + a1.x + a2.x + a3.x + bb.x;
      o.y = a0.y + a1.y + a2.y + a3.y + bb.y;
      o.z = a0.z + a1.z + a2.z + a3.z + bb.z;
      o.w = a0.w + a1.w + a2.w + a3.w + bb.w;
      *(float4*)&store[(obase + node)*(MM*DD) + m*DD + e2*4] = o;
    }
  }
}

// ---------------------------------------------------------------------------
// Eval: wave-per-node dot with w_eval (both m in one wave), stable BCE,
// float atomics into zeroed d_out = [loss(2), posOK(2), negOK(2)]
// ---------------------------------------------------------------------------
__global__ void eval_kernel(const float* __restrict__ store,
                            const float* __restrict__ pos_cnt, const float* __restrict__ neg_cnt,
                            const float* __restrict__ w_eval, const float* __restrict__ b_eval,
                            const float* __restrict__ totals, float* __restrict__ out)
{
  const int t = threadIdx.x, lane = t & 63;
  const int gw = blockIdx.x*(blockDim.x >> 6) + (t >> 6);
  const int nw = gridDim.x*(blockDim.x >> 6);
  float4 wv = *(const float4*)&w_eval[4*lane];          // lanes 0-31 -> m=0, 32-63 -> m=1
  const int m = (lane >= 32) ? 1 : 0;
  const float be = b_eval[m];
  const float tp = totals[0], tn = totals[1];
  const float pw = (tp > 0.f) ? (tn / fmaxf(tp, 1.f)) : 1.f;   // POS_WEIGHT_EXTRA = 1
  float loss = 0.f, pOK = 0.f, nOK = 0.f;
  for (int n = gw; n < NTOT; n += nw){
    float4 v = *(const float4*)&store[(size_t)n*(MM*DD) + 4*lane];
    float p = v.x*wv.x + v.y*wv.y + v.z*wv.z + v.w*wv.w;
    #pragma unroll
    for (int s = 1; s < 32; s <<= 1) p += __shfl_xor(p, s, 64);   // reduce within each m-half
    const float val = p + be;
    if ((lane & 31) == 0){
      const float pc = pos_cnt[n], nc = neg_cnt[n];
      const float cnt = pc + nc;
      if (cnt > 0.f){
        float gold = pc / fmaxf(cnt, 1.f);
        float e = log1pf(expf(-fabsf(val)));
        float sp_pos = e + fmaxf(val, 0.f);     // softplus(val)
        float sp_neg = e + fmaxf(-val, 0.f);    // softplus(-val)
        loss += cnt * (pw*gold*sp_neg + (1.f - gold)*sp_pos);
      }
      pOK += (val >= 0.f) ? pc : 0.f;
      nOK += (val <  0.f) ? nc : 0.f;
    }
  }
  if ((lane & 31) == 0){
    atomicAdd(&out[m],     loss);
    atomicAdd(&out[2 + m], pOK);
    atomicAdd(&out[4 + m], nOK);
  }
}

// ---------------------------------------------------------------------------
extern "C" void kernel_launch(void* const* d_in, const int* in_sizes, int n_in,
                              void* d_out, int out_size, void* d_ws, size_t ws_size,
                              hipStream_t stream)
{
  const int*   thax_ids   = (const int*)d_in[0];
  const int*   sine_ids   = (const int*)d_in[1];
  const int*   parents    = (const int*)d_in[2];
  const int*   rule_ids   = (const int*)d_in[3];
  const float* pos_cnt    = (const float*)d_in[4];
  const float* neg_cnt    = (const float*)d_in[5];
  const float* thax_table = (const float*)d_in[6];
  const float* sine_w     = (const float*)d_in[7];
  const float* sine_b     = (const float*)d_in[8];
  const float* W1         = (const float*)d_in[9];
  const float* b1         = (const float*)d_in[10];
  const float* W2         = (const float*)d_in[11];
  const float* b2         = (const float*)d_in[12];
  const float* w_eval     = (const float*)d_in[13];
  const float* b_eval     = (const float*)d_in[14];

  char* ws = (char*)d_ws;
  float* store = (float*)ws;
  size_t off = (size_t)NTOT*MM*DD*sizeof(float);            // 142.6 MB
  int* chunk_nodes = (int*)(ws + off); off += (size_t)LLV*CHN*NB*sizeof(int);
  int* chunk_rule  = (int*)(ws + off); off += (size_t)LLV*CHN*sizeof(int);
  int* nchunks     = (int*)(ws + off); off += (size_t)LLV*sizeof(int);
  float* totals    = (float*)(ws + off); off += 2*sizeof(float);

  hipMemsetAsync(d_out, 0, 6*sizeof(float), stream);
  hipMemsetAsync(totals, 0, 2*sizeof(float), stream);

  prep_kernel<<<LLV, 256, 0, stream>>>(rule_ids, chunk_nodes, chunk_rule, nchunks);
  init_kernel<<<(NN0*MM*DD + 255)/256, 256, 0, stream>>>(thax_ids, sine_ids, thax_table,
                                                         sine_w, sine_b, store);
  totals_kernel<<<64, 256, 0, stream>>>(pos_cnt, neg_cnt, totals);

  for (int l = 0; l < LLV; ++l)
    level_kernel<<<dim3(CHN, MM), 256, 0, stream>>>(store, parents, chunk_nodes, chunk_rule,
                                                    nchunks, W1, b1, W2, b2, l);

  eval_kernel<<<2048, 256, 0, stream>>>(store, pos_cnt, neg_cnt, w_eval, b_eval, totals, (float*)d_out);
}

// Round 6
// 1321.338 us; speedup vs baseline: 1.2280x; 1.0195x over previous
//
#include <hip/hip_runtime.h>
#include <cstdint>
#include <cstddef>

// Problem constants (match the JAX reference)
#define MM 2
#define DD 128
#define RR 8
#define NN0 8192
#define LLV 32
#define KK 4096
#define NTHAX 1000
#define NTOT (NN0 + LLV*KK)     // 139264
#define NB 16                   // nodes per chunk
#define CHN 264                 // max chunks per level: ceil((4096 + 8*15)/16) = 264
#define EBLK 2048               // eval blocks
#define TBLK 64                 // totals blocks

// ---------------------------------------------------------------------------
// Preprocess: per level, counting-sort node indices by rule into NB-padded
// chunks so each level-kernel block handles exactly one rule.
// ---------------------------------------------------------------------------
__global__ void prep_kernel(const int* __restrict__ rule_ids,
                            int* __restrict__ chunk_nodes,   // [LLV][CHN][NB]
                            int* __restrict__ chunk_rule,    // [LLV][CHN]
                            int* __restrict__ nchunks)       // [LLV]
{
  const int l = blockIdx.x, t = threadIdx.x;
  __shared__ int cnt[RR], start[RR], fill[RR];
  if (t < RR){ cnt[t] = 0; fill[t] = 0; }
  __syncthreads();
  for (int k = t; k < KK; k += blockDim.x) atomicAdd(&cnt[rule_ids[l*KK + k]], 1);
  __syncthreads();
  if (t == 0){
    int s = 0;
    for (int r = 0; r < RR; ++r){
      start[r] = s;
      int pad = (cnt[r] + NB - 1)/NB*NB;
      for (int c = s/NB; c < (s+pad)/NB; ++c) chunk_rule[l*CHN + c] = r;
      s += pad;
    }
    nchunks[l] = s/NB;
  }
  __syncthreads();
  for (int i = t; i < CHN*NB; i += blockDim.x) chunk_nodes[l*CHN*NB + i] = -1;
  __syncthreads();
  for (int k = t; k < KK; k += blockDim.x){
    int r = rule_ids[l*KK + k];
    int p = start[r] + atomicAdd(&fill[r], 1);   // LDS atomics only
    chunk_nodes[l*CHN*NB + p] = k;
  }
}

// ---------------------------------------------------------------------------
// Init nodes: store[i][m][d] = thax_table[m][thax[i]][d] * sigmoid(s*w + b)
// ---------------------------------------------------------------------------
__global__ void init_kernel(const int* __restrict__ thax_ids, const int* __restrict__ sine_ids,
                            const float* __restrict__ thax_table,
                            const float* __restrict__ sine_w, const float* __restrict__ sine_b,
                            float* __restrict__ store)
{
  int idx = blockIdx.x*blockDim.x + threadIdx.x;    // over NN0*MM*DD
  if (idx >= NN0*MM*DD) return;
  int i = idx >> 8;            // node
  int md = idx & 255;
  int m = md >> 7, d = md & 127;
  float emb = thax_table[((size_t)m*NTHAX + thax_ids[i])*DD + d];
  float s = (float)sine_ids[i];
  float z = s*sine_w[m*DD + d] + sine_b[m*DD + d];
  float sig = 1.f/(1.f + expf(-z));
  store[idx] = emb*sig;
}

// ---------------------------------------------------------------------------
// Totals: per-block partial sums of pos/neg (no atomics)
// pt layout: [2][TBLK]  (comp 0 = tot_pos, 1 = tot_neg)
// ---------------------------------------------------------------------------
__global__ void totals_kernel(const float* __restrict__ pos, const float* __restrict__ neg,
                              float* __restrict__ pt)
{
  __shared__ float ts[4][2];
  const int t = threadIdx.x, lane = t & 63;
  float sp = 0.f, sn = 0.f;
  for (int n = blockIdx.x*blockDim.x + t; n < NTOT; n += gridDim.x*blockDim.x){
    sp += pos[n]; sn += neg[n];
  }
  #pragma unroll
  for (int s = 1; s < 64; s <<= 1){ sp += __shfl_xor(sp, s, 64); sn += __shfl_xor(sn, s, 64); }
  if (lane == 0){ ts[t>>6][0] = sp; ts[t>>6][1] = sn; }
  __syncthreads();
  if (t < 2) pt[t*TBLK + blockIdx.x] = ts[0][t] + ts[1][t] + ts[2][t] + ts[3][t];
}

// ---------------------------------------------------------------------------
// One level, structure C + register double-buffer prefetch:
//   block = (chunk of 16 same-rule nodes, member m), 256 threads = 4 waves.
//   wave ks (0..3) owns a K-quarter; thread = (ej 0..31, ni 0..1) computes
//   8 nodes x 4 outputs (32 acc).  x/w for step kl+4 are loaded while step kl
//   computes, hiding L2/L3 latency.  Per-layer LDS reduction sums quarters.
// ---------------------------------------------------------------------------
__global__ __launch_bounds__(256, 3) void level_kernel(
    float* __restrict__ store,
    const int* __restrict__ parents,      // [LLV][KK][2]
    const int* __restrict__ chunk_nodes,  // [LLV][CHN][NB]
    const int* __restrict__ chunk_rule,   // [LLV][CHN]
    const int* __restrict__ nchunks,      // [LLV]
    const float* __restrict__ W1, const float* __restrict__ b1,
    const float* __restrict__ W2, const float* __restrict__ b2,
    int level)
{
  const int c = blockIdx.x;
  if (c >= nchunks[level]) return;
  const int m = blockIdx.y;
  const int r = chunk_rule[level*CHN + c];

  __shared__ float RED[4][NB][32][4];   // 32 KB: [ks][node][ej][4e] partials
  __shared__ float Hlds[NB][DD];        // 8 KB : layer-1 activations
  __shared__ int nd[NB];
  __shared__ int par[NB][2];

  const int t  = threadIdx.x;
  const int ej = t & 31;
  const int ni = (t >> 5) & 1;
  const int ks = t >> 6;                // wave index = K-quarter
  const int e0 = ej * 4;

  if (t < NB){
    int node = chunk_nodes[(level*CHN + c)*NB + t];
    nd[t] = node;
    const int* parL = parents + (size_t)level*KK*2;
    int p0 = 0, p1 = 0;
    if (node >= 0){ p0 = parL[node*2]; p1 = parL[node*2 + 1]; }
    par[t][0] = p0; par[t][1] = p1;
  }
  __syncthreads();

  // ---------------- Layer 1: K rows [ks*64, ks*64+64) ----------------
  const float* W1p = W1 + (size_t)(m*RR + r)*(2*DD)*DD + (size_t)(ks*64)*DD;
  const int psel = ks >> 1, koff = (ks & 1)*64;

  int xoff[8];
  #pragma unroll
  for (int j = 0; j < 8; ++j)
    xoff[j] = par[ni*8 + j][psel]*(MM*DD) + m*DD + koff;

  float acc[8][4];
  #pragma unroll
  for (int j = 0; j < 8; ++j){ acc[j][0]=0.f; acc[j][1]=0.f; acc[j][2]=0.f; acc[j][3]=0.f; }

  // preload step 0
  float4 xq[8], wq[4];
  #pragma unroll
  for (int j = 0; j < 8; ++j) xq[j] = *(const float4*)(store + xoff[j]);
  #pragma unroll
  for (int i = 0; i < 4; ++i) wq[i] = *(const float4*)&W1p[(size_t)i*DD + e0];

  #pragma unroll
  for (int kl = 0; kl < 64; kl += 4){
    float4 xn[8], wn[4];
    if (kl + 4 < 64){
      #pragma unroll
      for (int j = 0; j < 8; ++j) xn[j] = *(const float4*)(store + xoff[j] + kl + 4);
      #pragma unroll
      for (int i = 0; i < 4; ++i) wn[i] = *(const float4*)&W1p[(size_t)(kl + 4 + i)*DD + e0];
    }
    #pragma unroll
    for (int i = 0; i < 4; ++i){
      float4 w4 = wq[i];
      #pragma unroll
      for (int j = 0; j < 8; ++j){
        float xv = (i==0) ? xq[j].x : (i==1) ? xq[j].y : (i==2) ? xq[j].z : xq[j].w;
        acc[j][0] = fmaf(xv, w4.x, acc[j][0]);
        acc[j][1] = fmaf(xv, w4.y, acc[j][1]);
        acc[j][2] = fmaf(xv, w4.z, acc[j][2]);
        acc[j][3] = fmaf(xv, w4.w, acc[j][3]);
      }
    }
    if (kl + 4 < 64){
      #pragma unroll
      for (int j = 0; j < 8; ++j) xq[j] = xn[j];
      #pragma unroll
      for (int i = 0; i < 4; ++i) wq[i] = wn[i];
    }
  }

  #pragma unroll
  for (int j = 0; j < 8; ++j)
    *(float4*)&RED[ks][ni*8 + j][ej][0] = make_float4(acc[j][0], acc[j][1], acc[j][2], acc[j][3]);
  __syncthreads();

  // reduce 4 K-quarters, add bias, relu, write Hlds.  512 sets, 2 per thread.
  {
    const float* b1p = b1 + (m*RR + r)*DD;
    #pragma unroll
    for (int s2 = 0; s2 < 2; ++s2){
      int s = t*2 + s2;                 // 0..511
      int n = s >> 5, e2 = s & 31;
      float4 a0 = *(const float4*)&RED[0][n][e2][0];
      float4 a1 = *(const float4*)&RED[1][n][e2][0];
      float4 a2 = *(const float4*)&RED[2][n][e2][0];
      float4 a3 = *(const float4*)&RED[3][n][e2][0];
      float4 bb = *(const float4*)&b1p[e2*4];
      float4 h;
      h.x = fmaxf(a0.x + a1.x + a2.x + a3.x + bb.x, 0.f);
      h.y = fmaxf(a0.y + a1.y + a2.y + a3.y + bb.y, 0.f);
      h.z = fmaxf(a0.z + a1.z + a2.z + a3.z + bb.z, 0.f);
      h.w = fmaxf(a0.w + a1.w + a2.w + a3.w + bb.w, 0.f);
      *(float4*)&Hlds[n][e2*4] = h;
    }
  }
  __syncthreads();

  // ---------------- Layer 2: K rows [ks*32, ks*32+32) ----------------
  const float* W2p = W2 + (size_t)(m*RR + r)*DD*DD + (size_t)(ks*32)*DD;

  #pragma unroll
  for (int j = 0; j < 8; ++j){ acc[j][0]=0.f; acc[j][1]=0.f; acc[j][2]=0.f; acc[j][3]=0.f; }

  #pragma unroll
  for (int kl = 0; kl < 32; kl += 4){
    float4 xq2[8];
    #pragma unroll
    for (int j = 0; j < 8; ++j) xq2[j] = *(const float4*)&Hlds[ni*8 + j][ks*32 + kl];
    #pragma unroll
    for (int i = 0; i < 4; ++i){
      float4 w4 = *(const float4*)&W2p[(size_t)(kl + i)*DD + e0];
      #pragma unroll
      for (int j = 0; j < 8; ++j){
        float xv = (i==0) ? xq2[j].x : (i==1) ? xq2[j].y : (i==2) ? xq2[j].z : xq2[j].w;
        acc[j][0] = fmaf(xv, w4.x, acc[j][0]);
        acc[j][1] = fmaf(xv, w4.y, acc[j][1]);
        acc[j][2] = fmaf(xv, w4.z, acc[j][2]);
        acc[j][3] = fmaf(xv, w4.w, acc[j][3]);
      }
    }
  }

  #pragma unroll
  for (int j = 0; j < 8; ++j)
    *(float4*)&RED[ks][ni*8 + j][ej][0] = make_float4(acc[j][0], acc[j][1], acc[j][2], acc[j][3]);
  __syncthreads();

  // reduce, add b2, write result rows to store
  {
    const float* b2p = b2 + (m*RR + r)*DD;
    const size_t obase = (size_t)(NN0 + level*KK);
    #pragma unroll
    for (int s2 = 0; s2 < 2; ++s2){
      int s = t*2 + s2;
      int n = s >> 5, e2 = s & 31;
      int node = nd[n];
      if (node < 0) continue;
      float4 a0 = *(const float4*)&RED[0][n][e2][0];
      float4 a1 = *(const float4*)&RED[1][n][e2][0];
      float4 a2 = *(const float4*)&RED[2][n][e2][0];
      float4 a3 = *(const float4*)&RED[3][n][e2][0];
      float4 bb = *(const float4*)&b2p[e2*4];
      float4 o;
      o.x = a0.x + a1.x + a2.x + a3.x + bb.x;
      o.y = a0.y + a1.y + a2.y + a3.y + bb.y;
      o.z = a0.z + a1.z + a2.z + a3.z + bb.z;
      o.w = a0.w + a1.w + a2.w + a3.w + bb.w;
      *(float4*)&store[(obase + node)*(MM*DD) + m*DD + e2*4] = o;
    }
  }
}

// ---------------------------------------------------------------------------
// Eval: wave-per-node dot with w_eval (both m in one wave), stable BCE.
// Writes per-block partials (NO atomics): pe[c][blk], c = q*2 + m,
// q: 0=A (pw-weighted loss part), 1=B, 2=posOK, 3=negOK.
// loss = pw*A + B is assembled in finish_kernel (pw factors out).
// ---------------------------------------------------------------------------
__global__ void eval_kernel(const float* __restrict__ store,
                            const float* __restrict__ pos_cnt, const float* __restrict__ neg_cnt,
                            const float* __restrict__ w_eval, const float* __restrict__ b_eval,
                            float* __restrict__ pe)
{
  __shared__ float part[4][2][4];      // [wave][m][q]
  const int t = threadIdx.x, lane = t & 63;
  const int gw = blockIdx.x*(blockDim.x >> 6) + (t >> 6);
  const int nw = gridDim.x*(blockDim.x >> 6);
  float4 wv = *(const float4*)&w_eval[4*lane];          // lanes 0-31 -> m=0, 32-63 -> m=1
  const int m = (lane >= 32) ? 1 : 0;
  const float be = b_eval[m];
  float A = 0.f, B = 0.f, pOK = 0.f, nOK = 0.f;
  for (int n = gw; n < NTOT; n += nw){
    float4 v = *(const float4*)&store[(size_t)n*(MM*DD) + 4*lane];
    float p = v.x*wv.x + v.y*wv.y + v.z*wv.z + v.w*wv.w;
    #pragma unroll
    for (int s = 1; s < 32; s <<= 1) p += __shfl_xor(p, s, 64);   // reduce within each m-half
    const float val = p + be;
    if ((lane & 31) == 0){
      const float pc = pos_cnt[n], nc = neg_cnt[n];
      const float cnt = pc + nc;
      if (cnt > 0.f){
        float gold = pc / fmaxf(cnt, 1.f);
        float e = log1pf(expf(-fabsf(val)));
        float sp_pos = e + fmaxf(val, 0.f);     // softplus(val)
        float sp_neg = e + fmaxf(-val, 0.f);    // softplus(-val)
        A += cnt * gold * sp_neg;
        B += cnt * (1.f - gold) * sp_pos;
      }
      pOK += (val >= 0.f) ? pc : 0.f;
      nOK += (val <  0.f) ? nc : 0.f;
    }
  }
  if ((lane & 31) == 0){
    int w = t >> 6;
    part[w][m][0] = A; part[w][m][1] = B; part[w][m][2] = pOK; part[w][m][3] = nOK;
  }
  __syncthreads();
  if (t < 8){
    int q = t >> 1, mm = t & 1;
    float s = part[0][mm][q] + part[1][mm][q] + part[2][mm][q] + part[3][mm][q];
    pe[t*EBLK + blockIdx.x] = s;
  }
}

// ---------------------------------------------------------------------------
// Finish: reduce totals partials + eval partials, compute pw, write 6 outputs.
// ---------------------------------------------------------------------------
__global__ void finish_kernel(const float* __restrict__ pt, const float* __restrict__ pe,
                              float* __restrict__ out)
{
  __shared__ float acc8[8];
  __shared__ float tt[2];
  const int t = threadIdx.x;             // 256
  if (t < 64){                           // totals: comp c = t>>5, lanes t&31
    int c = t >> 5, l = t & 31;
    float s = pt[c*TBLK + l] + pt[c*TBLK + l + 32];
    #pragma unroll
    for (int d = 1; d < 32; d <<= 1) s += __shfl_xor(s, d, 64);
    if (l == 0) tt[c] = s;
  }
  {
    int comp = t >> 5, l = t & 31;
    float s = 0.f;
    for (int i = 0; i < EBLK/32; ++i) s += pe[comp*EBLK + i*32 + l];
    #pragma unroll
    for (int d = 1; d < 32; d <<= 1) s += __shfl_xor(s, d, 64);
    if (l == 0) acc8[comp] = s;
  }
  __syncthreads();
  if (t < 2){                            // m = t
    float tp = tt[0], tn = tt[1];
    float pw = (tp > 0.f) ? (tn / fmaxf(tp, 1.f)) : 1.f;   // POS_WEIGHT_EXTRA = 1
    out[t]     = pw*acc8[0 + t] + acc8[2 + t];
    out[2 + t] = acc8[4 + t];
    out[4 + t] = acc8[6 + t];
  }
}

// ---------------------------------------------------------------------------
extern "C" void kernel_launch(void* const* d_in, const int* in_sizes, int n_in,
                              void* d_out, int out_size, void* d_ws, size_t ws_size,
                              hipStream_t stream)
{
  const int*   thax_ids   = (const int*)d_in[0];
  const int*   sine_ids   = (const int*)d_in[1];
  const int*   parents    = (const int*)d_in[2];
  const int*   rule_ids   = (const int*)d_in[3];
  const float* pos_cnt    = (const float*)d_in[4];
  const float* neg_cnt    = (const float*)d_in[5];
  const float* thax_table = (const float*)d_in[6];
  const float* sine_w     = (const float*)d_in[7];
  const float* sine_b     = (const float*)d_in[8];
  const float* W1         = (const float*)d_in[9];
  const float* b1         = (const float*)d_in[10];
  const float* W2         = (const float*)d_in[11];
  const float* b2         = (const float*)d_in[12];
  const float* w_eval     = (const float*)d_in[13];
  const float* b_eval     = (const float*)d_in[14];

  char* ws = (char*)d_ws;
  float* store = (float*)ws;
  size_t off = (size_t)NTOT*MM*DD*sizeof(float);            // 142.6 MB
  int* chunk_nodes = (int*)(ws + off); off += (size_t)LLV*CHN*NB*sizeof(int);
  int* chunk_rule  = (int*)(ws + off); off += (size_t)LLV*CHN*sizeof(int);
  int* nchunks     = (int*)(ws + off); off += (size_t)LLV*sizeof(int);
  float* pt        = (float*)(ws + off); off += (size_t)2*TBLK*sizeof(float);
  float* pe        = (float*)(ws + off); off += (size_t)8*EBLK*sizeof(float);

  prep_kernel<<<LLV, 256, 0, stream>>>(rule_ids, chunk_nodes, chunk_rule, nchunks);
  init_kernel<<<(NN0*MM*DD + 255)/256, 256, 0, stream>>>(thax_ids, sine_ids, thax_table,
                                                         sine_w, sine_b, store);
  totals_kernel<<<TBLK, 256, 0, stream>>>(pos_cnt, neg_cnt, pt);

  for (int l = 0; l < LLV; ++l)
    level_kernel<<<dim3(CHN, MM), 256, 0, stream>>>(store, parents, chunk_nodes, chunk_rule,
                                                    nchunks, W1, b1, W2, b2, l);

  eval_kernel<<<EBLK, 256, 0, stream>>>(store, pos_cnt, neg_cnt, w_eval, b_eval, pe);
  finish_kernel<<<1, 256, 0, stream>>>(pt, pe, (float*)d_out);
}

// Round 8
// 1201.614 us; speedup vs baseline: 1.3504x; 1.0996x over previous
//
#include <hip/hip_runtime.h>
#include <cstdint>
#include <cstddef>

// Problem constants (match the JAX reference)
#define MM 2
#define DD 128
#define RR 8
#define NN0 8192
#define LLV 32
#define KK 4096
#define NTHAX 1000
#define NTOT (NN0 + LLV*KK)     // 139264
#define NB 8                    // nodes per chunk
#define CHN8 520                // max chunks/level: ceil((4096 + 8*7)/8) = 519 -> 520
#define GRIDL 1040              // level grid (8 XCDs x 130 slots)
#define XCAP (GRIDL/8)          // 130 slots per XCD
#define EBLK 2048               // eval blocks
#define TBLK 64                 // totals blocks

// ---------------------------------------------------------------------------
// Preprocess: per level, counting-sort nodes by rule into NB-padded chunks,
// then build a block->(chunk,member) map that pins rule r to XCD r (b%8==r)
// so each XCD's L2 only streams 2 weight matrices (384 KB) per level.
// ---------------------------------------------------------------------------
__global__ void prep_kernel(const int* __restrict__ rule_ids,
                            int* __restrict__ chunk_nodes,   // [LLV][CHN8][NB]
                            int* __restrict__ chunk_rule,    // [LLV][CHN8]
                            int* __restrict__ blk2c,         // [LLV][GRIDL]
                            int* __restrict__ blk2m)         // [LLV][GRIDL]
{
  const int l = blockIdx.x, t = threadIdx.x;
  __shared__ int cnt[RR], start[RR], fill[RR];
  __shared__ int s_nch;
  if (t < RR){ cnt[t] = 0; fill[t] = 0; }
  __syncthreads();
  for (int k = t; k < KK; k += blockDim.x) atomicAdd(&cnt[rule_ids[l*KK + k]], 1);
  __syncthreads();
  if (t == 0){
    int s = 0;
    for (int r = 0; r < RR; ++r){
      start[r] = s;
      int pad = (cnt[r] + NB - 1)/NB*NB;
      for (int c = s/NB; c < (s+pad)/NB; ++c) chunk_rule[l*CHN8 + c] = r;
      s += pad;
    }
    s_nch = s/NB;
  }
  __syncthreads();
  for (int i = t; i < CHN8*NB; i += blockDim.x) chunk_nodes[l*CHN8*NB + i] = -1;
  for (int i = t; i < GRIDL; i += blockDim.x){ blk2c[l*GRIDL + i] = -1; }
  __syncthreads();
  for (int k = t; k < KK; k += blockDim.x){
    int r = rule_ids[l*KK + k];
    int p = start[r] + atomicAdd(&fill[r], 1);   // LDS atomics only
    chunk_nodes[l*CHN8*NB + p] = k;
  }
  __syncthreads();
  if (t == 0){
    // place (chunk, member) pairs: home XCD = rule; spill to next free XCD.
    int used[8] = {0,0,0,0,0,0,0,0};
    int* bc = blk2c + l*GRIDL;
    int* bm = blk2m + l*GRIDL;
    const int nch = s_nch;
    for (int m = 0; m < MM; ++m){
      for (int c = 0; c < nch; ++c){
        int x = chunk_rule[l*CHN8 + c] & 7;
        int tries = 0;
        while (used[x] >= XCAP && tries < 8){ x = (x + 1) & 7; ++tries; }
        int b = used[x]*8 + x; used[x]++;
        bc[b] = c; bm[b] = m;
      }
    }
  }
}

// ---------------------------------------------------------------------------
// Init nodes: store[i][m][d] = thax_table[m][thax[i]][d] * sigmoid(s*w + b)
// ---------------------------------------------------------------------------
__global__ void init_kernel(const int* __restrict__ thax_ids, const int* __restrict__ sine_ids,
                            const float* __restrict__ thax_table,
                            const float* __restrict__ sine_w, const float* __restrict__ sine_b,
                            float* __restrict__ store)
{
  int idx = blockIdx.x*blockDim.x + threadIdx.x;    // over NN0*MM*DD
  if (idx >= NN0*MM*DD) return;
  int i = idx >> 8;            // node
  int md = idx & 255;
  int m = md >> 7, d = md & 127;
  float emb = thax_table[((size_t)m*NTHAX + thax_ids[i])*DD + d];
  float s = (float)sine_ids[i];
  float z = s*sine_w[m*DD + d] + sine_b[m*DD + d];
  float sig = 1.f/(1.f + expf(-z));
  store[idx] = emb*sig;
}

// ---------------------------------------------------------------------------
// Totals: per-block partial sums of pos/neg (no atomics)
// ---------------------------------------------------------------------------
__global__ void totals_kernel(const float* __restrict__ pos, const float* __restrict__ neg,
                              float* __restrict__ pt)
{
  __shared__ float ts[4][2];
  const int t = threadIdx.x, lane = t & 63;
  float sp = 0.f, sn = 0.f;
  for (int n = blockIdx.x*blockDim.x + t; n < NTOT; n += gridDim.x*blockDim.x){
    sp += pos[n]; sn += neg[n];
  }
  #pragma unroll
  for (int s = 1; s < 64; s <<= 1){ sp += __shfl_xor(sp, s, 64); sn += __shfl_xor(sn, s, 64); }
  if (lane == 0){ ts[t>>6][0] = sp; ts[t>>6][1] = sn; }
  __syncthreads();
  if (t < 2) pt[t*TBLK + blockIdx.x] = ts[0][t] + ts[1][t] + ts[2][t] + ts[3][t];
}

// ---------------------------------------------------------------------------
// One level: block = one (chunk of 8 same-rule nodes, member m) from blk2c map.
// 4 waves; wave ks owns a K-quarter; thread = (ej, ni) computes 4 nodes x 4 e.
// Register double-buffer prefetch on x and w.  LDS reduce per layer.
// Epilogue/reduce: one float4 per consecutive thread (full-line writes).
// ---------------------------------------------------------------------------
__global__ __launch_bounds__(256, 4) void level_kernel(
    float* __restrict__ store,
    const int* __restrict__ parents,      // [LLV][KK][2]
    const int* __restrict__ chunk_nodes,  // [LLV][CHN8][NB]
    const int* __restrict__ chunk_rule,   // [LLV][CHN8]
    const int* __restrict__ blk2c,        // [LLV][GRIDL]
    const int* __restrict__ blk2m,        // [LLV][GRIDL]
    const float* __restrict__ W1, const float* __restrict__ b1,
    const float* __restrict__ W2, const float* __restrict__ b2,
    int level)
{
  const int c = blk2c[level*GRIDL + blockIdx.x];
  if (c < 0) return;
  const int m = blk2m[level*GRIDL + blockIdx.x];
  const int r = chunk_rule[level*CHN8 + c];

  __shared__ float RED[4][NB][32][4];   // 16 KB: [ks][node][ej][4e] partials
  __shared__ float Hlds[NB][DD];        // 4 KB : layer-1 activations
  __shared__ int nd[NB];
  __shared__ int par[NB][2];

  const int t  = threadIdx.x;
  const int ej = t & 31;
  const int ni = (t >> 5) & 1;
  const int ks = t >> 6;                // wave index = K-quarter
  const int e0 = ej * 4;

  if (t < NB){
    int node = chunk_nodes[(level*CHN8 + c)*NB + t];
    nd[t] = node;
    const int* parL = parents + (size_t)level*KK*2;
    int p0 = 0, p1 = 0;
    if (node >= 0){ p0 = parL[node*2]; p1 = parL[node*2 + 1]; }
    par[t][0] = p0; par[t][1] = p1;
  }
  __syncthreads();

  // ---------------- Layer 1: K rows [ks*64, ks*64+64) ----------------
  const float* W1p = W1 + (size_t)(m*RR + r)*(2*DD)*DD + (size_t)(ks*64)*DD;
  const int psel = ks >> 1, koff = (ks & 1)*64;

  int xoff[4];
  #pragma unroll
  for (int j = 0; j < 4; ++j)
    xoff[j] = par[ni*4 + j][psel]*(MM*DD) + m*DD + koff;

  float acc[4][4];
  #pragma unroll
  for (int j = 0; j < 4; ++j){ acc[j][0]=0.f; acc[j][1]=0.f; acc[j][2]=0.f; acc[j][3]=0.f; }

  // preload step 0
  float4 xq[4], wq[4];
  #pragma unroll
  for (int j = 0; j < 4; ++j) xq[j] = *(const float4*)(store + xoff[j]);
  #pragma unroll
  for (int i = 0; i < 4; ++i) wq[i] = *(const float4*)&W1p[(size_t)i*DD + e0];

  #pragma unroll
  for (int kl = 0; kl < 64; kl += 4){
    float4 xn[4], wn[4];
    if (kl + 4 < 64){
      #pragma unroll
      for (int j = 0; j < 4; ++j) xn[j] = *(const float4*)(store + xoff[j] + kl + 4);
      #pragma unroll
      for (int i = 0; i < 4; ++i) wn[i] = *(const float4*)&W1p[(size_t)(kl + 4 + i)*DD + e0];
    }
    #pragma unroll
    for (int i = 0; i < 4; ++i){
      float4 w4 = wq[i];
      #pragma unroll
      for (int j = 0; j < 4; ++j){
        float xv = (i==0) ? xq[j].x : (i==1) ? xq[j].y : (i==2) ? xq[j].z : xq[j].w;
        acc[j][0] = fmaf(xv, w4.x, acc[j][0]);
        acc[j][1] = fmaf(xv, w4.y, acc[j][1]);
        acc[j][2] = fmaf(xv, w4.z, acc[j][2]);
        acc[j][3] = fmaf(xv, w4.w, acc[j][3]);
      }
    }
    if (kl + 4 < 64){
      #pragma unroll
      for (int j = 0; j < 4; ++j) xq[j] = xn[j];
      #pragma unroll
      for (int i = 0; i < 4; ++i) wq[i] = wn[i];
    }
  }

  #pragma unroll
  for (int j = 0; j < 4; ++j)
    *(float4*)&RED[ks][ni*4 + j][ej][0] = make_float4(acc[j][0], acc[j][1], acc[j][2], acc[j][3]);
  __syncthreads();

  // reduce 4 K-quarters, add bias, relu -> Hlds.  256 sets, 1 per thread.
  {
    const float* b1p = b1 + (m*RR + r)*DD;
    int n = t >> 5, e2 = t & 31;
    float4 a0 = *(const float4*)&RED[0][n][e2][0];
    float4 a1 = *(const float4*)&RED[1][n][e2][0];
    float4 a2 = *(const float4*)&RED[2][n][e2][0];
    float4 a3 = *(const float4*)&RED[3][n][e2][0];
    float4 bb = *(const float4*)&b1p[e2*4];
    float4 h;
    h.x = fmaxf(a0.x + a1.x + a2.x + a3.x + bb.x, 0.f);
    h.y = fmaxf(a0.y + a1.y + a2.y + a3.y + bb.y, 0.f);
    h.z = fmaxf(a0.z + a1.z + a2.z + a3.z + bb.z, 0.f);
    h.w = fmaxf(a0.w + a1.w + a2.w + a3.w + bb.w, 0.f);
    *(float4*)&Hlds[n][e2*4] = h;
  }
  __syncthreads();

  // ---------------- Layer 2: K rows [ks*32, ks*32+32) ----------------
  const float* W2p = W2 + (size_t)(m*RR + r)*DD*DD + (size_t)(ks*32)*DD;

  #pragma unroll
  for (int j = 0; j < 4; ++j){ acc[j][0]=0.f; acc[j][1]=0.f; acc[j][2]=0.f; acc[j][3]=0.f; }

  #pragma unroll
  for (int kl = 0; kl < 32; kl += 4){
    float4 xq2[4];
    #pragma unroll
    for (int j = 0; j < 4; ++j) xq2[j] = *(const float4*)&Hlds[ni*4 + j][ks*32 + kl];
    #pragma unroll
    for (int i = 0; i < 4; ++i){
      float4 w4 = *(const float4*)&W2p[(size_t)(kl + i)*DD + e0];
      #pragma unroll
      for (int j = 0; j < 4; ++j){
        float xv = (i==0) ? xq2[j].x : (i==1) ? xq2[j].y : (i==2) ? xq2[j].z : xq2[j].w;
        acc[j][0] = fmaf(xv, w4.x, acc[j][0]);
        acc[j][1] = fmaf(xv, w4.y, acc[j][1]);
        acc[j][2] = fmaf(xv, w4.z, acc[j][2]);
        acc[j][3] = fmaf(xv, w4.w, acc[j][3]);
      }
    }
  }

  #pragma unroll
  for (int j = 0; j < 4; ++j)
    *(float4*)&RED[ks][ni*4 + j][ej][0] = make_float4(acc[j][0], acc[j][1], acc[j][2], acc[j][3]);
  __syncthreads();

  // reduce, add b2, write result rows (1 float4 per thread, coalesced)
  {
    const float* b2p = b2 + (m*RR + r)*DD;
    const size_t obase = (size_t)(NN0 + level*KK);
    int n = t >> 5, e2 = t & 31;
    int node = nd[n];
    if (node >= 0){
      float4 a0 = *(const float4*)&RED[0][n][e2][0];
      float4 a1 = *(const float4*)&RED[1][n][e2][0];
      float4 a2 = *(const float4*)&RED[2][n][e2][0];
      float4 a3 = *(const float4*)&RED[3][n][e2][0];
      float4 bb = *(const float4*)&b2p[e2*4];
      float4 o;
      o.x = a0.x + a1.x + a2.x + a3.x + bb.x;
      o.y = a0.y + a1.y + a2.y + a3.y + bb.y;
      o.z = a0.z + a1.z + a2.z + a3.z + bb.z;
      o.w = a0.w + a1.w + a2.w + a3.w + bb.w;
      *(float4*)&store[(obase + node)*(MM*DD) + m*DD + e2*4] = o;
    }
  }
}

// ---------------------------------------------------------------------------
// Eval: wave-per-node dot with w_eval (both m in one wave), stable BCE.
// Per-block partials (NO atomics): pe[c][blk], c = q*2 + m,
// q: 0=A (pw part), 1=B, 2=posOK, 3=negOK.  loss = pw*A + B in finish.
// ---------------------------------------------------------------------------
__global__ void eval_kernel(const float* __restrict__ store,
                            const float* __restrict__ pos_cnt, const float* __restrict__ neg_cnt,
                            const float* __restrict__ w_eval, const float* __restrict__ b_eval,
                            float* __restrict__ pe)
{
  __shared__ float part[4][2][4];      // [wave][m][q]
  const int t = threadIdx.x, lane = t & 63;
  const int gw = blockIdx.x*(blockDim.x >> 6) + (t >> 6);
  const int nw = gridDim.x*(blockDim.x >> 6);
  float4 wv = *(const float4*)&w_eval[4*lane];          // lanes 0-31 -> m=0, 32-63 -> m=1
  const int m = (lane >= 32) ? 1 : 0;
  const float be = b_eval[m];
  float A = 0.f, B = 0.f, pOK = 0.f, nOK = 0.f;
  for (int n = gw; n < NTOT; n += nw){
    float4 v = *(const float4*)&store[(size_t)n*(MM*DD) + 4*lane];
    float p = v.x*wv.x + v.y*wv.y + v.z*wv.z + v.w*wv.w;
    #pragma unroll
    for (int s = 1; s < 32; s <<= 1) p += __shfl_xor(p, s, 64);   // reduce within each m-half
    const float val = p + be;
    if ((lane & 31) == 0){
      const float pc = pos_cnt[n], nc = neg_cnt[n];
      const float cnt = pc + nc;
      if (cnt > 0.f){
        float gold = pc / fmaxf(cnt, 1.f);
        float e = log1pf(expf(-fabsf(val)));
        float sp_pos = e + fmaxf(val, 0.f);     // softplus(val)
        float sp_neg = e + fmaxf(-val, 0.f);    // softplus(-val)
        A += cnt * gold * sp_neg;
        B += cnt * (1.f - gold) * sp_pos;
      }
      pOK += (val >= 0.f) ? pc : 0.f;
      nOK += (val <  0.f) ? nc : 0.f;
    }
  }
  if ((lane & 31) == 0){
    int w = t >> 6;
    part[w][m][0] = A; part[w][m][1] = B; part[w][m][2] = pOK; part[w][m][3] = nOK;
  }
  __syncthreads();
  if (t < 8){
    int q = t >> 1, mm = t & 1;
    float s = part[0][mm][q] + part[1][mm][q] + part[2][mm][q] + part[3][mm][q];
    pe[t*EBLK + blockIdx.x] = s;
  }
}

// ---------------------------------------------------------------------------
// Finish: reduce totals + eval partials, compute pw, write 6 outputs.
// ---------------------------------------------------------------------------
__global__ void finish_kernel(const float* __restrict__ pt, const float* __restrict__ pe,
                              float* __restrict__ out)
{
  __shared__ float acc8[8];
  __shared__ float tt[2];
  const int t = threadIdx.x;             // 256
  if (t < 64){                           // totals: comp c = t>>5
    int c = t >> 5, l = t & 31;
    float s = pt[c*TBLK + l] + pt[c*TBLK + l + 32];
    #pragma unroll
    for (int d = 1; d < 32; d <<= 1) s += __shfl_xor(s, d, 64);
    if (l == 0) tt[c] = s;
  }
  {
    int comp = t >> 5, l = t & 31;
    float s = 0.f;
    for (int i = 0; i < EBLK/32; ++i) s += pe[comp*EBLK + i*32 + l];
    #pragma unroll
    for (int d = 1; d < 32; d <<= 1) s += __shfl_xor(s, d, 64);
    if (l == 0) acc8[comp] = s;
  }
  __syncthreads();
  if (t < 2){                            // m = t
    float tp = tt[0], tn = tt[1];
    float pw = (tp > 0.f) ? (tn / fmaxf(tp, 1.f)) : 1.f;   // POS_WEIGHT_EXTRA = 1
    out[t]     = pw*acc8[0 + t] + acc8[2 + t];
    out[2 + t] = acc8[4 + t];
    out[4 + t] = acc8[6 + t];
  }
}

// ---------------------------------------------------------------------------
extern "C" void kernel_launch(void* const* d_in, const int* in_sizes, int n_in,
                              void* d_out, int out_size, void* d_ws, size_t ws_size,
                              hipStream_t stream)
{
  const int*   thax_ids   = (const int*)d_in[0];
  const int*   sine_ids   = (const int*)d_in[1];
  const int*   parents    = (const int*)d_in[2];
  const int*   rule_ids   = (const int*)d_in[3];
  const float* pos_cnt    = (const float*)d_in[4];
  const float* neg_cnt    = (const float*)d_in[5];
  const float* thax_table = (const float*)d_in[6];
  const float* sine_w     = (const float*)d_in[7];
  const float* sine_b     = (const float*)d_in[8];
  const float* W1         = (const float*)d_in[9];
  const float* b1         = (const float*)d_in[10];
  const float* W2         = (const float*)d_in[11];
  const float* b2         = (const float*)d_in[12];
  const float* w_eval     = (const float*)d_in[13];
  const float* b_eval     = (const float*)d_in[14];

  char* ws = (char*)d_ws;
  float* store = (float*)ws;
  size_t off = (size_t)NTOT*MM*DD*sizeof(float);            // 142.6 MB
  int* chunk_nodes = (int*)(ws + off); off += (size_t)LLV*CHN8*NB*sizeof(int);
  int* chunk_rule  = (int*)(ws + off); off += (size_t)LLV*CHN8*sizeof(int);
  int* blk2c       = (int*)(ws + off); off += (size_t)LLV*GRIDL*sizeof(int);
  int* blk2m       = (int*)(ws + off); off += (size_t)LLV*GRIDL*sizeof(int);
  float* pt        = (float*)(ws + off); off += (size_t)2*TBLK*sizeof(float);
  float* pe        = (float*)(ws + off); off += (size_t)8*EBLK*sizeof(float);

  prep_kernel<<<LLV, 256, 0, stream>>>(rule_ids, chunk_nodes, chunk_rule, blk2c, blk2m);
  init_kernel<<<(NN0*MM*DD + 255)/256, 256, 0, stream>>>(thax_ids, sine_ids, thax_table,
                                                         sine_w, sine_b, store);
  totals_kernel<<<TBLK, 256, 0, stream>>>(pos_cnt, neg_cnt, pt);

  for (int l = 0; l < LLV; ++l)
    level_kernel<<<GRIDL, 256, 0, stream>>>(store, parents, chunk_nodes, chunk_rule,
                                            blk2c, blk2m, W1, b1, W2, b2, l);

  eval_kernel<<<EBLK, 256, 0, stream>>>(store, pos_cnt, neg_cnt, w_eval, b_eval, pe);
  finish_kernel<<<1, 256, 0, stream>>>(pt, pe, (float*)d_out);
}

// Round 9
// 783.032 us; speedup vs baseline: 2.0722x; 1.5346x over previous
//
#include <hip/hip_runtime.h>
#include <cstdint>
#include <cstddef>

// Problem constants (match the JAX reference)
#define MM 2
#define DD 128
#define RR 8
#define NN0 8192
#define LLV 32
#define KK 4096
#define NTHAX 1000
#define NTOT (NN0 + LLV*KK)     // 139264
#define NB 8                    // nodes per chunk
#define CHN8 520                // max chunks/level: ceil((4096 + 8*7)/8) = 519 -> 520
#define EBLK 2048               // eval blocks
#define TBLK 64                 // totals blocks

// ---------------------------------------------------------------------------
// Preprocess: per level, counting-sort node indices by rule into NB-padded
// chunks so each level-kernel block handles exactly one rule.  (No placement
// map: the serial thread-0 placement loop cost 236 us in round 8.)
// ---------------------------------------------------------------------------
__global__ void prep_kernel(const int* __restrict__ rule_ids,
                            int* __restrict__ chunk_nodes,   // [LLV][CHN8][NB]
                            int* __restrict__ chunk_rule,    // [LLV][CHN8]
                            int* __restrict__ nchunks)       // [LLV]
{
  const int l = blockIdx.x, t = threadIdx.x;
  __shared__ int cnt[RR], start[RR], fill[RR];
  if (t < RR){ cnt[t] = 0; fill[t] = 0; }
  __syncthreads();
  for (int k = t; k < KK; k += blockDim.x) atomicAdd(&cnt[rule_ids[l*KK + k]], 1);
  __syncthreads();
  if (t == 0){
    int s = 0;
    for (int r = 0; r < RR; ++r){
      start[r] = s;
      int pad = (cnt[r] + NB - 1)/NB*NB;
      for (int c = s/NB; c < (s+pad)/NB; ++c) chunk_rule[l*CHN8 + c] = r;
      s += pad;
    }
    nchunks[l] = s/NB;
  }
  __syncthreads();
  for (int i = t; i < CHN8*NB; i += blockDim.x) chunk_nodes[l*CHN8*NB + i] = -1;
  __syncthreads();
  for (int k = t; k < KK; k += blockDim.x){
    int r = rule_ids[l*KK + k];
    int p = start[r] + atomicAdd(&fill[r], 1);   // LDS atomics only
    chunk_nodes[l*CHN8*NB + p] = k;
  }
}

// ---------------------------------------------------------------------------
// Init nodes: store[i][m][d] = thax_table[m][thax[i]][d] * sigmoid(s*w + b)
// ---------------------------------------------------------------------------
__global__ void init_kernel(const int* __restrict__ thax_ids, const int* __restrict__ sine_ids,
                            const float* __restrict__ thax_table,
                            const float* __restrict__ sine_w, const float* __restrict__ sine_b,
                            float* __restrict__ store)
{
  int idx = blockIdx.x*blockDim.x + threadIdx.x;    // over NN0*MM*DD
  if (idx >= NN0*MM*DD) return;
  int i = idx >> 8;            // node
  int md = idx & 255;
  int m = md >> 7, d = md & 127;
  float emb = thax_table[((size_t)m*NTHAX + thax_ids[i])*DD + d];
  float s = (float)sine_ids[i];
  float z = s*sine_w[m*DD + d] + sine_b[m*DD + d];
  float sig = 1.f/(1.f + expf(-z));
  store[idx] = emb*sig;
}

// ---------------------------------------------------------------------------
// Totals: per-block partial sums of pos/neg (no atomics)
// ---------------------------------------------------------------------------
__global__ void totals_kernel(const float* __restrict__ pos, const float* __restrict__ neg,
                              float* __restrict__ pt)
{
  __shared__ float ts[4][2];
  const int t = threadIdx.x, lane = t & 63;
  float sp = 0.f, sn = 0.f;
  for (int n = blockIdx.x*blockDim.x + t; n < NTOT; n += gridDim.x*blockDim.x){
    sp += pos[n]; sn += neg[n];
  }
  #pragma unroll
  for (int s = 1; s < 64; s <<= 1){ sp += __shfl_xor(sp, s, 64); sn += __shfl_xor(sn, s, 64); }
  if (lane == 0){ ts[t>>6][0] = sp; ts[t>>6][1] = sn; }
  __syncthreads();
  if (t < 2) pt[t*TBLK + blockIdx.x] = ts[0][t] + ts[1][t] + ts[2][t] + ts[3][t];
}

// ---------------------------------------------------------------------------
// One level: block = (chunk of 8 same-rule nodes, member m).
// Step 1: stage all parent X vectors to LDS (8 KB, coalesced, one latency hit).
// Step 2: 4 waves; wave ks owns a K-quarter; thread = (ej, ni) computes
//         4 nodes x 4 e with x from LDS broadcast + depth-2 weight prefetch.
// LDS reduce per layer; coalesced float4 epilogue (full-line writes).
// ---------------------------------------------------------------------------
__global__ __launch_bounds__(256, 4) void level_kernel(
    float* __restrict__ store,
    const int* __restrict__ parents,      // [LLV][KK][2]
    const int* __restrict__ chunk_nodes,  // [LLV][CHN8][NB]
    const int* __restrict__ chunk_rule,   // [LLV][CHN8]
    const int* __restrict__ nchunks,      // [LLV]
    const float* __restrict__ W1, const float* __restrict__ b1,
    const float* __restrict__ W2, const float* __restrict__ b2,
    int level)
{
  const int c = blockIdx.x;
  if (c >= nchunks[level]) return;
  const int m = blockIdx.y;
  const int r = chunk_rule[level*CHN8 + c];

  __shared__ float Xs[NB][2*DD];        //  8 KB: concatenated parent vectors
  __shared__ float RED[4][NB][32][4];   // 16 KB: [ks][node][ej][4e] partials
  __shared__ float Hlds[NB][DD];        //  4 KB: layer-1 activations
  __shared__ int nd[NB];
  __shared__ int par[NB][2];

  const int t  = threadIdx.x;
  const int ej = t & 31;
  const int ni = (t >> 5) & 1;
  const int ks = t >> 6;                // wave index = K-quarter
  const int e0 = ej * 4;

  if (t < NB){
    int node = chunk_nodes[(level*CHN8 + c)*NB + t];
    nd[t] = node;
    const int* parL = parents + (size_t)level*KK*2;
    int p0 = 0, p1 = 0;
    if (node >= 0){ p0 = parL[node*2]; p1 = parL[node*2 + 1]; }
    par[t][0] = p0; par[t][1] = p1;
  }
  __syncthreads();

  // ---- Stage X: 512 float4s, 2 per thread, coalesced 512B runs ----
  #pragma unroll
  for (int q4 = 0; q4 < 2; ++q4){
    int q = q4*256 + t;                 // 0..511
    int n = q >> 6, dq = q & 63;        // dq = float4 index within 256-float row
    int p = par[n][dq >> 5];
    int col = (dq & 31) * 4;
    float4 v = *(const float4*)(store + (size_t)p*(MM*DD) + m*DD + col);
    *(float4*)&Xs[n][dq*4] = v;
  }
  __syncthreads();

  // ---------------- Layer 1: K rows [ks*64, ks*64+64) ----------------
  const float* W1p = W1 + (size_t)(m*RR + r)*(2*DD)*DD + (size_t)(ks*64)*DD;

  float acc[4][4];
  #pragma unroll
  for (int j = 0; j < 4; ++j){ acc[j][0]=0.f; acc[j][1]=0.f; acc[j][2]=0.f; acc[j][3]=0.f; }

  // depth-2 weight prefetch: wA = rows kl..kl+3, wB = rows kl+4..kl+7
  float4 wA[4], wB[4];
  #pragma unroll
  for (int i = 0; i < 4; ++i){
    wA[i] = *(const float4*)&W1p[(size_t)i*DD + e0];
    wB[i] = *(const float4*)&W1p[(size_t)(4 + i)*DD + e0];
  }
  #pragma unroll
  for (int kl = 0; kl < 64; kl += 8){
    // half 1: rows kl..kl+3 (wA)
    {
      float4 xv[4];
      #pragma unroll
      for (int j = 0; j < 4; ++j) xv[j] = *(const float4*)&Xs[ni*4 + j][ks*64 + kl];
      #pragma unroll
      for (int i = 0; i < 4; ++i){
        float4 w4 = wA[i];
        #pragma unroll
        for (int j = 0; j < 4; ++j){
          float xs = (i==0) ? xv[j].x : (i==1) ? xv[j].y : (i==2) ? xv[j].z : xv[j].w;
          acc[j][0] = fmaf(xs, w4.x, acc[j][0]);
          acc[j][1] = fmaf(xs, w4.y, acc[j][1]);
          acc[j][2] = fmaf(xs, w4.z, acc[j][2]);
          acc[j][3] = fmaf(xs, w4.w, acc[j][3]);
        }
      }
      if (kl + 8 < 64){
        #pragma unroll
        for (int i = 0; i < 4; ++i) wA[i] = *(const float4*)&W1p[(size_t)(kl + 8 + i)*DD + e0];
      }
    }
    // half 2: rows kl+4..kl+7 (wB)
    {
      float4 xv[4];
      #pragma unroll
      for (int j = 0; j < 4; ++j) xv[j] = *(const float4*)&Xs[ni*4 + j][ks*64 + kl + 4];
      #pragma unroll
      for (int i = 0; i < 4; ++i){
        float4 w4 = wB[i];
        #pragma unroll
        for (int j = 0; j < 4; ++j){
          float xs = (i==0) ? xv[j].x : (i==1) ? xv[j].y : (i==2) ? xv[j].z : xv[j].w;
          acc[j][0] = fmaf(xs, w4.x, acc[j][0]);
          acc[j][1] = fmaf(xs, w4.y, acc[j][1]);
          acc[j][2] = fmaf(xs, w4.z, acc[j][2]);
          acc[j][3] = fmaf(xs, w4.w, acc[j][3]);
        }
      }
      if (kl + 12 < 64){
        #pragma unroll
        for (int i = 0; i < 4; ++i) wB[i] = *(const float4*)&W1p[(size_t)(kl + 12 + i)*DD + e0];
      }
    }
  }

  #pragma unroll
  for (int j = 0; j < 4; ++j)
    *(float4*)&RED[ks][ni*4 + j][ej][0] = make_float4(acc[j][0], acc[j][1], acc[j][2], acc[j][3]);
  __syncthreads();

  // reduce 4 K-quarters, add bias, relu -> Hlds.  256 sets, 1 per thread.
  {
    const float* b1p = b1 + (m*RR + r)*DD;
    int n = t >> 5, e2 = t & 31;
    float4 a0 = *(const float4*)&RED[0][n][e2][0];
    float4 a1 = *(const float4*)&RED[1][n][e2][0];
    float4 a2 = *(const float4*)&RED[2][n][e2][0];
    float4 a3 = *(const float4*)&RED[3][n][e2][0];
    float4 bb = *(const float4*)&b1p[e2*4];
    float4 h;
    h.x = fmaxf(a0.x + a1.x + a2.x + a3.x + bb.x, 0.f);
    h.y = fmaxf(a0.y + a1.y + a2.y + a3.y + bb.y, 0.f);
    h.z = fmaxf(a0.z + a1.z + a2.z + a3.z + bb.z, 0.f);
    h.w = fmaxf(a0.w + a1.w + a2.w + a3.w + bb.w, 0.f);
    *(float4*)&Hlds[n][e2*4] = h;
  }
  __syncthreads();

  // ---------------- Layer 2: K rows [ks*32, ks*32+32) ----------------
  const float* W2p = W2 + (size_t)(m*RR + r)*DD*DD + (size_t)(ks*32)*DD;

  #pragma unroll
  for (int j = 0; j < 4; ++j){ acc[j][0]=0.f; acc[j][1]=0.f; acc[j][2]=0.f; acc[j][3]=0.f; }

  #pragma unroll
  for (int i = 0; i < 4; ++i){
    wA[i] = *(const float4*)&W2p[(size_t)i*DD + e0];
    wB[i] = *(const float4*)&W2p[(size_t)(4 + i)*DD + e0];
  }
  #pragma unroll
  for (int kl = 0; kl < 32; kl += 8){
    {
      float4 xv[4];
      #pragma unroll
      for (int j = 0; j < 4; ++j) xv[j] = *(const float4*)&Hlds[ni*4 + j][ks*32 + kl];
      #pragma unroll
      for (int i = 0; i < 4; ++i){
        float4 w4 = wA[i];
        #pragma unroll
        for (int j = 0; j < 4; ++j){
          float xs = (i==0) ? xv[j].x : (i==1) ? xv[j].y : (i==2) ? xv[j].z : xv[j].w;
          acc[j][0] = fmaf(xs, w4.x, acc[j][0]);
          acc[j][1] = fmaf(xs, w4.y, acc[j][1]);
          acc[j][2] = fmaf(xs, w4.z, acc[j][2]);
          acc[j][3] = fmaf(xs, w4.w, acc[j][3]);
        }
      }
      if (kl + 8 < 32){
        #pragma unroll
        for (int i = 0; i < 4; ++i) wA[i] = *(const float4*)&W2p[(size_t)(kl + 8 + i)*DD + e0];
      }
    }
    {
      float4 xv[4];
      #pragma unroll
      for (int j = 0; j < 4; ++j) xv[j] = *(const float4*)&Hlds[ni*4 + j][ks*32 + kl + 4];
      #pragma unroll
      for (int i = 0; i < 4; ++i){
        float4 w4 = wB[i];
        #pragma unroll
        for (int j = 0; j < 4; ++j){
          float xs = (i==0) ? xv[j].x : (i==1) ? xv[j].y : (i==2) ? xv[j].z : xv[j].w;
          acc[j][0] = fmaf(xs, w4.x, acc[j][0]);
          acc[j][1] = fmaf(xs, w4.y, acc[j][1]);
          acc[j][2] = fmaf(xs, w4.z, acc[j][2]);
          acc[j][3] = fmaf(xs, w4.w, acc[j][3]);
        }
      }
      if (kl + 12 < 32){
        #pragma unroll
        for (int i = 0; i < 4; ++i) wB[i] = *(const float4*)&W2p[(size_t)(kl + 12 + i)*DD + e0];
      }
    }
  }

  #pragma unroll
  for (int j = 0; j < 4; ++j)
    *(float4*)&RED[ks][ni*4 + j][ej][0] = make_float4(acc[j][0], acc[j][1], acc[j][2], acc[j][3]);
  __syncthreads();

  // reduce, add b2, write result rows (1 float4 per thread, coalesced)
  {
    const float* b2p = b2 + (m*RR + r)*DD;
    const size_t obase = (size_t)(NN0 + level*KK);
    int n = t >> 5, e2 = t & 31;
    int node = nd[n];
    if (node >= 0){
      float4 a0 = *(const float4*)&RED[0][n][e2][0];
      float4 a1 = *(const float4*)&RED[1][n][e2][0];
      float4 a2 = *(const float4*)&RED[2][n][e2][0];
      float4 a3 = *(const float4*)&RED[3][n][e2][0];
      float4 bb = *(const float4*)&b2p[e2*4];
      float4 o;
      o.x = a0.x + a1.x + a2.x + a3.x + bb.x;
      o.y = a0.y + a1.y + a2.y + a3.y + bb.y;
      o.z = a0.z + a1.z + a2.z + a3.z + bb.z;
      o.w = a0.w + a1.w + a2.w + a3.w + bb.w;
      *(float4*)&store[(obase + node)*(MM*DD) + m*DD + e2*4] = o;
    }
  }
}

// ---------------------------------------------------------------------------
// Eval: wave-per-node dot with w_eval (both m in one wave), stable BCE.
// Per-block partials (NO atomics): pe[c][blk], c = q*2 + m,
// q: 0=A (pw part), 1=B, 2=posOK, 3=negOK.  loss = pw*A + B in finish.
// ---------------------------------------------------------------------------
__global__ void eval_kernel(const float* __restrict__ store,
                            const float* __restrict__ pos_cnt, const float* __restrict__ neg_cnt,
                            const float* __restrict__ w_eval, const float* __restrict__ b_eval,
                            float* __restrict__ pe)
{
  __shared__ float part[4][2][4];      // [wave][m][q]
  const int t = threadIdx.x, lane = t & 63;
  const int gw = blockIdx.x*(blockDim.x >> 6) + (t >> 6);
  const int nw = gridDim.x*(blockDim.x >> 6);
  float4 wv = *(const float4*)&w_eval[4*lane];          // lanes 0-31 -> m=0, 32-63 -> m=1
  const int m = (lane >= 32) ? 1 : 0;
  const float be = b_eval[m];
  float A = 0.f, B = 0.f, pOK = 0.f, nOK = 0.f;
  for (int n = gw; n < NTOT; n += nw){
    float4 v = *(const float4*)&store[(size_t)n*(MM*DD) + 4*lane];
    float p = v.x*wv.x + v.y*wv.y + v.z*wv.z + v.w*wv.w;
    #pragma unroll
    for (int s = 1; s < 32; s <<= 1) p += __shfl_xor(p, s, 64);   // reduce within each m-half
    const float val = p + be;
    if ((lane & 31) == 0){
      const float pc = pos_cnt[n], nc = neg_cnt[n];
      const float cnt = pc + nc;
      if (cnt > 0.f){
        float gold = pc / fmaxf(cnt, 1.f);
        float e = log1pf(expf(-fabsf(val)));
        float sp_pos = e + fmaxf(val, 0.f);     // softplus(val)
        float sp_neg = e + fmaxf(-val, 0.f);    // softplus(-val)
        A += cnt * gold * sp_neg;
        B += cnt * (1.f - gold) * sp_pos;
      }
      pOK += (val >= 0.f) ? pc : 0.f;
      nOK += (val <  0.f) ? nc : 0.f;
    }
  }
  if ((lane & 31) == 0){
    int w = t >> 6;
    part[w][m][0] = A; part[w][m][1] = B; part[w][m][2] = pOK; part[w][m][3] = nOK;
  }
  __syncthreads();
  if (t < 8){
    int q = t >> 1, mm = t & 1;
    float s = part[0][mm][q] + part[1][mm][q] + part[2][mm][q] + part[3][mm][q];
    pe[t*EBLK + blockIdx.x] = s;
  }
}

// ---------------------------------------------------------------------------
// Finish: reduce totals + eval partials, compute pw, write 6 outputs.
// ---------------------------------------------------------------------------
__global__ void finish_kernel(const float* __restrict__ pt, const float* __restrict__ pe,
                              float* __restrict__ out)
{
  __shared__ float acc8[8];
  __shared__ float tt[2];
  const int t = threadIdx.x;             // 256
  if (t < 64){                           // totals: comp c = t>>5
    int c = t >> 5, l = t & 31;
    float s = pt[c*TBLK + l] + pt[c*TBLK + l + 32];
    #pragma unroll
    for (int d = 1; d < 32; d <<= 1) s += __shfl_xor(s, d, 64);
    if (l == 0) tt[c] = s;
  }
  {
    int comp = t >> 5, l = t & 31;
    float s = 0.f;
    for (int i = 0; i < EBLK/32; ++i) s += pe[comp*EBLK + i*32 + l];
    #pragma unroll
    for (int d = 1; d < 32; d <<= 1) s += __shfl_xor(s, d, 64);
    if (l == 0) acc8[comp] = s;
  }
  __syncthreads();
  if (t < 2){                            // m = t
    float tp = tt[0], tn = tt[1];
    float pw = (tp > 0.f) ? (tn / fmaxf(tp, 1.f)) : 1.f;   // POS_WEIGHT_EXTRA = 1
    out[t]     = pw*acc8[0 + t] + acc8[2 + t];
    out[2 + t] = acc8[4 + t];
    out[4 + t] = acc8[6 + t];
  }
}

// ---------------------------------------------------------------------------
extern "C" void kernel_launch(void* const* d_in, const int* in_sizes, int n_in,
                              void* d_out, int out_size, void* d_ws, size_t ws_size,
                              hipStream_t stream)
{
  const int*   thax_ids   = (const int*)d_in[0];
  const int*   sine_ids   = (const int*)d_in[1];
  const int*   parents    = (const int*)d_in[2];
  const int*   rule_ids   = (const int*)d_in[3];
  const float* pos_cnt    = (const float*)d_in[4];
  const float* neg_cnt    = (const float*)d_in[5];
  const float* thax_table = (const float*)d_in[6];
  const float* sine_w     = (const float*)d_in[7];
  const float* sine_b     = (const float*)d_in[8];
  const float* W1         = (const float*)d_in[9];
  const float* b1         = (const float*)d_in[10];
  const float* W2         = (const float*)d_in[11];
  const float* b2         = (const float*)d_in[12];
  const float* w_eval     = (const float*)d_in[13];
  const float* b_eval     = (const float*)d_in[14];

  char* ws = (char*)d_ws;
  float* store = (float*)ws;
  size_t off = (size_t)NTOT*MM*DD*sizeof(float);            // 142.6 MB
  int* chunk_nodes = (int*)(ws + off); off += (size_t)LLV*CHN8*NB*sizeof(int);
  int* chunk_rule  = (int*)(ws + off); off += (size_t)LLV*CHN8*sizeof(int);
  int* nchunks     = (int*)(ws + off); off += (size_t)LLV*sizeof(int);
  float* pt        = (float*)(ws + off); off += (size_t)2*TBLK*sizeof(float);
  float* pe        = (float*)(ws + off); off += (size_t)8*EBLK*sizeof(float);

  prep_kernel<<<LLV, 256, 0, stream>>>(rule_ids, chunk_nodes, chunk_rule, nchunks);
  init_kernel<<<(NN0*MM*DD + 255)/256, 256, 0, stream>>>(thax_ids, sine_ids, thax_table,
                                                         sine_w, sine_b, store);
  totals_kernel<<<TBLK, 256, 0, stream>>>(pos_cnt, neg_cnt, pt);

  for (int l = 0; l < LLV; ++l)
    level_kernel<<<dim3(CHN8, MM), 256, 0, stream>>>(store, parents, chunk_nodes, chunk_rule,
                                                     nchunks, W1, b1, W2, b2, l);

  eval_kernel<<<EBLK, 256, 0, stream>>>(store, pos_cnt, neg_cnt, w_eval, b_eval, pe);
  finish_kernel<<<1, 256, 0, stream>>>(pt, pe, (float*)d_out);
}